// Round 1
// baseline (4259.887 us; speedup 1.0000x reference)
//
#include <hip/hip_runtime.h>
#include <cstdint>
#include <cstddef>

#define NN 100000
#define NE 800000
#define NG 256
#define NL 5
#define EPS 1e-5f

// ---------------- init: h = atom_emb[x] ----------------
__global__ __launch_bounds__(256) void init_h_k(const int* __restrict__ x,
                                                const float* __restrict__ atom_emb,
                                                float* __restrict__ h) {
  int i = blockIdx.x * 256 + threadIdx.x;       // over NN*16 float4 slots
  if (i >= NN * 16) return;
  int n = i >> 4, c4 = i & 15;
  float4 v = *(const float4*)(atom_emb + (size_t)x[n] * 64 + c4 * 4);
  *(float4*)(h + (size_t)n * 64 + c4 * 4) = v;
}

// ---------------- edge scatter: aggr[dst] += relu(h[src] + bond[eattr]) ----------------
__global__ __launch_bounds__(256) void edge_aggr_k(const int* __restrict__ ei,
                                                   const int* __restrict__ eattr,
                                                   const float* __restrict__ bond,
                                                   const float* __restrict__ h,
                                                   float* __restrict__ aggr) {
  int i = blockIdx.x * 256 + threadIdx.x;       // over NE*16
  int e = i >> 4, c4 = i & 15;
  if (e >= NE) return;
  int s = ei[e];
  int d = ei[NE + e];
  int b = eattr[e];
  float4 hv = *(const float4*)(h + (size_t)s * 64 + c4 * 4);
  float4 bv = *(const float4*)(bond + (size_t)b * 64 + c4 * 4);
  float* ap = aggr + (size_t)d * 64 + c4 * 4;
  atomicAdd(ap + 0, fmaxf(hv.x + bv.x, 0.f));
  atomicAdd(ap + 1, fmaxf(hv.y + bv.y, 0.f));
  atomicAdd(ap + 2, fmaxf(hv.z + bv.z, 0.f));
  atomicAdd(ap + 3, fmaxf(hv.w + bv.w, 0.f));
}

// ---------------- gemm1: z1 = (h + aggr) @ W1 + b1   (K=64 -> 128 cols) ----------------
__global__ __launch_bounds__(256) void gemm1_k(const float* __restrict__ h,
                                               const float* __restrict__ aggr,
                                               const float* __restrict__ W,
                                               const float* __restrict__ bias,
                                               float* __restrict__ z1) {
  __shared__ float Ws[64 * 128];   // 32 KB
  __shared__ float Xs[32][72];     // padded stride 72 (2-way max on reads)
  int tid = threadIdx.x;
  for (int j = tid; j < 64 * 128 / 4; j += 256)
    ((float4*)Ws)[j] = ((const float4*)W)[j];
  int row0 = blockIdx.x * 32;      // 3125 * 32 == 100000 exactly
  for (int j = tid; j < 32 * 16; j += 256) {
    int r = j >> 4, c4 = j & 15;
    size_t n = (size_t)row0 + r;
    float4 a = *(const float4*)(h + n * 64 + c4 * 4);
    float4 g = *(const float4*)(aggr + n * 64 + c4 * 4);
    *(float4*)&Xs[r][c4 * 4] = make_float4(a.x + g.x, a.y + g.y, a.z + g.z, a.w + g.w);
  }
  __syncthreads();
  int c0 = (tid & 15) * 8;
  int r0 = (tid >> 4) * 2;
  float acc0[8], acc1[8];
#pragma unroll
  for (int j = 0; j < 8; ++j) { acc0[j] = 0.f; acc1[j] = 0.f; }
#pragma unroll 4
  for (int k = 0; k < 64; ++k) {
    float a0 = Xs[r0][k];
    float a1 = Xs[r0 + 1][k];
    const float* wr = &Ws[k * 128 + c0];
    float4 w0 = *(const float4*)(wr);
    float4 w1 = *(const float4*)(wr + 4);
    float w[8] = {w0.x, w0.y, w0.z, w0.w, w1.x, w1.y, w1.z, w1.w};
#pragma unroll
    for (int j = 0; j < 8; ++j) {
      acc0[j] = fmaf(a0, w[j], acc0[j]);
      acc1[j] = fmaf(a1, w[j], acc1[j]);
    }
  }
  float4 bb0 = *(const float4*)(bias + c0);
  float4 bb1 = *(const float4*)(bias + c0 + 4);
  float bb[8] = {bb0.x, bb0.y, bb0.z, bb0.w, bb1.x, bb1.y, bb1.z, bb1.w};
#pragma unroll
  for (int rr = 0; rr < 2; ++rr) {
    size_t n = (size_t)row0 + r0 + rr;
    float* zp = z1 + n * 128 + c0;
    float* a = rr == 0 ? acc0 : acc1;
    *(float4*)(zp)     = make_float4(a[0] + bb[0], a[1] + bb[1], a[2] + bb[2], a[3] + bb[3]);
    *(float4*)(zp + 4) = make_float4(a[4] + bb[4], a[5] + bb[5], a[6] + bb[6], a[7] + bb[7]);
  }
}

// ---------------- column stats (sum, sumsq) in f64 ----------------
template <int C>
__global__ __launch_bounds__(256) void col_stats_k(const float* __restrict__ z,
                                                   double* __restrict__ stats) {
  const int RPB = 256 / C;
  int tid = threadIdx.x;
  int c = tid % C;
  int rw = tid / C;
  double s = 0.0, s2 = 0.0;
  for (int r = blockIdx.x * RPB + rw; r < NN; r += gridDim.x * RPB) {
    float v = z[(size_t)r * C + c];
    s += (double)v;
    s2 += (double)v * (double)v;
  }
  __shared__ double sh[2][256];
  sh[0][tid] = s; sh[1][tid] = s2;
  __syncthreads();
  for (int off = 128; off >= C; off >>= 1) {
    if (tid < off) { sh[0][tid] += sh[0][tid + off]; sh[1][tid] += sh[1][tid + off]; }
    __syncthreads();
  }
  if (tid < C) {
    atomicAdd(&stats[c], sh[0][tid]);
    atomicAdd(&stats[C + c], sh[1][tid]);
  }
}

// ---------------- finalize BN -> per-column scale/shift ----------------
__global__ void finalize_bn_k(const double* __restrict__ stats,
                              const float* __restrict__ g,
                              const float* __restrict__ be,
                              float* __restrict__ scale,
                              float* __restrict__ shift, int C) {
  int c = threadIdx.x;
  if (c < C) {
    double mean = stats[c] * (1.0 / NN);
    double var = stats[C + c] * (1.0 / NN) - mean * mean;
    float sc = g[c] * rsqrtf((float)var + EPS);
    scale[c] = sc;
    shift[c] = be[c] - (float)mean * sc;
  }
}

// ---------------- gemm2: z2 = relu(z1*scale+shift) @ W2 + b2  (K=128 -> 64 cols) ----------------
__global__ __launch_bounds__(256) void gemm2_k(const float* __restrict__ z1,
                                               const float* __restrict__ scale,
                                               const float* __restrict__ shift,
                                               const float* __restrict__ W,
                                               const float* __restrict__ bias,
                                               float* __restrict__ z2) {
  __shared__ float Ws[128 * 64];   // 32 KB
  __shared__ float Xs[32][132];    // padded stride 132 (conflict-free reads)
  int tid = threadIdx.x;
  for (int j = tid; j < 128 * 64 / 4; j += 256)
    ((float4*)Ws)[j] = ((const float4*)W)[j];
  int row0 = blockIdx.x * 32;
  for (int j = tid; j < 32 * 32; j += 256) {
    int r = j >> 5, c4 = j & 31;
    size_t n = (size_t)row0 + r;
    float4 v = *(const float4*)(z1 + n * 128 + c4 * 4);
    float4 sc = *(const float4*)(scale + c4 * 4);
    float4 sf = *(const float4*)(shift + c4 * 4);
    v.x = fmaxf(fmaf(v.x, sc.x, sf.x), 0.f);
    v.y = fmaxf(fmaf(v.y, sc.y, sf.y), 0.f);
    v.z = fmaxf(fmaf(v.z, sc.z, sf.z), 0.f);
    v.w = fmaxf(fmaf(v.w, sc.w, sf.w), 0.f);
    *(float4*)&Xs[r][c4 * 4] = v;
  }
  __syncthreads();
  int c0 = (tid & 7) * 8;
  int r = tid >> 3;
  float acc[8];
#pragma unroll
  for (int j = 0; j < 8; ++j) acc[j] = 0.f;
#pragma unroll 4
  for (int k = 0; k < 128; ++k) {
    float a = Xs[r][k];
    const float* wr = &Ws[k * 64 + c0];
    float4 w0 = *(const float4*)(wr);
    float4 w1 = *(const float4*)(wr + 4);
    float w[8] = {w0.x, w0.y, w0.z, w0.w, w1.x, w1.y, w1.z, w1.w};
#pragma unroll
    for (int j = 0; j < 8; ++j) acc[j] = fmaf(a, w[j], acc[j]);
  }
  float4 bb0 = *(const float4*)(bias + c0);
  float4 bb1 = *(const float4*)(bias + c0 + 4);
  size_t n = (size_t)row0 + r;
  float* zp = z2 + n * 64 + c0;
  *(float4*)(zp)     = make_float4(acc[0] + bb0.x, acc[1] + bb0.y, acc[2] + bb0.z, acc[3] + bb0.w);
  *(float4*)(zp + 4) = make_float4(acc[4] + bb1.x, acc[5] + bb1.y, acc[6] + bb1.z, acc[7] + bb1.w);
}

// ---------------- apply BN2 (+optional relu) -> h ----------------
__global__ __launch_bounds__(256) void bn_apply_k(const float* __restrict__ z2,
                                                  const float* __restrict__ scale,
                                                  const float* __restrict__ shift,
                                                  float* __restrict__ h, int do_relu) {
  int i = blockIdx.x * 256 + threadIdx.x;       // over NN*16
  if (i >= NN * 16) return;
  int c4 = i & 15;
  float4 v = ((const float4*)z2)[i];
  float4 sc = *(const float4*)(scale + c4 * 4);
  float4 sf = *(const float4*)(shift + c4 * 4);
  v.x = fmaf(v.x, sc.x, sf.x);
  v.y = fmaf(v.y, sc.y, sf.y);
  v.z = fmaf(v.z, sc.z, sf.z);
  v.w = fmaf(v.w, sc.w, sf.w);
  if (do_relu) {
    v.x = fmaxf(v.x, 0.f); v.y = fmaxf(v.y, 0.f);
    v.z = fmaxf(v.z, 0.f); v.w = fmaxf(v.w, 0.f);
  }
  ((float4*)h)[i] = v;
}

// ---------------- pool: xpool[batch[n]] += h[n]  (batch sorted) ----------------
__global__ __launch_bounds__(256) void pool_k(const float* __restrict__ h,
                                              const int* __restrict__ batch,
                                              float* __restrict__ xpool) {
  int n0 = blockIdx.x * 16;
  int tid = threadIdx.x;
  int r = tid >> 4, c4 = tid & 15;
  int n = n0 + r;                                // 6250*16 == 100000 exactly
  float4 v = *(const float4*)(h + (size_t)n * 64 + c4 * 4);
  __shared__ int gfirst, gsame;
  __shared__ float red[16][64];
  if (tid == 0) {
    gfirst = batch[n0];
    gsame = (batch[n0] == batch[n0 + 15]) ? 1 : 0;
  }
  *(float4*)&red[r][c4 * 4] = v;
  __syncthreads();
  if (gsame) {
#pragma unroll
    for (int off = 8; off >= 1; off >>= 1) {
      if (r < off) {
        float4 a = *(float4*)&red[r][c4 * 4];
        float4 b = *(float4*)&red[r + off][c4 * 4];
        *(float4*)&red[r][c4 * 4] = make_float4(a.x + b.x, a.y + b.y, a.z + b.z, a.w + b.w);
      }
      __syncthreads();
    }
    if (r == 0) {
      float* p = xpool + (size_t)gfirst * 64 + c4 * 4;
      float4 a = *(float4*)&red[0][c4 * 4];
      atomicAdd(p + 0, a.x); atomicAdd(p + 1, a.y);
      atomicAdd(p + 2, a.z); atomicAdd(p + 3, a.w);
    }
  } else {
    int g = batch[n];
    float* p = xpool + (size_t)g * 64 + c4 * 4;
    atomicAdd(p + 0, v.x); atomicAdd(p + 1, v.y);
    atomicAdd(p + 2, v.z); atomicAdd(p + 3, v.w);
  }
}

extern "C" void kernel_launch(void* const* d_in, const int* in_sizes, int n_in,
                              void* d_out, int out_size, void* d_ws, size_t ws_size,
                              hipStream_t stream) {
  const int* batch = (const int*)d_in[0];
  const int* x = (const int*)d_in[1];
  const int* ei = (const int*)d_in[2];
  const int* eattr = (const int*)d_in[3];
  const float* atom_emb = (const float*)d_in[4];
  const float* bond_emb = (const float*)d_in[5];
  const float* W1 = (const float*)d_in[6];
  const float* b1 = (const float*)d_in[7];
  const float* g1 = (const float*)d_in[8];
  const float* be1 = (const float*)d_in[9];
  const float* W2 = (const float*)d_in[10];
  const float* b2 = (const float*)d_in[11];
  const float* gbn = (const float*)d_in[12];
  const float* bbn = (const float*)d_in[13];

  float* out = (float*)d_out;
  float* xpool = out;              // 256*64
  float* h = out + NG * 64;        // N*64, final h lives directly in output

  char* ws = (char*)d_ws;
  float* aggr = (float*)ws;                          // N*64 f32 = 25.6 MB
  float* z1 = (float*)(ws + (size_t)25600000);       // N*128 f32 = 51.2 MB
  double* stat1 = (double*)(ws + (size_t)76800000);  // 256 doubles
  double* stat2 = stat1 + 256;                       // 128 doubles
  float* ssbuf = (float*)(ws + (size_t)76800000 + 3072);
  float* scale1 = ssbuf, *shift1 = ssbuf + 128;
  float* scale2 = ssbuf + 256, *shift2 = ssbuf + 320;
  float* z2 = aggr;                                  // alias: aggr dead after gemm1

  init_h_k<<<(NN * 16 + 255) / 256, 256, 0, stream>>>(x, atom_emb, h);

  for (int l = 0; l < NL; ++l) {
    hipMemsetAsync(aggr, 0, (size_t)NN * 64 * 4, stream);
    hipMemsetAsync(stat1, 0, 3072, stream);
    edge_aggr_k<<<(NE * 16 + 255) / 256, 256, 0, stream>>>(ei, eattr, bond_emb, h, aggr);
    gemm1_k<<<NN / 32, 256, 0, stream>>>(h, aggr, W1 + (size_t)l * 64 * 128,
                                         b1 + (size_t)l * 128, z1);
    col_stats_k<128><<<1024, 256, 0, stream>>>(z1, stat1);
    finalize_bn_k<<<1, 128, 0, stream>>>(stat1, g1 + (size_t)l * 128, be1 + (size_t)l * 128,
                                         scale1, shift1, 128);
    gemm2_k<<<NN / 32, 256, 0, stream>>>(z1, scale1, shift1, W2 + (size_t)l * 128 * 64,
                                         b2 + (size_t)l * 64, z2);
    col_stats_k<64><<<1024, 256, 0, stream>>>(z2, stat2);
    finalize_bn_k<<<1, 64, 0, stream>>>(stat2, gbn + (size_t)l * 64, bbn + (size_t)l * 64,
                                        scale2, shift2, 64);
    bn_apply_k<<<(NN * 16 + 255) / 256, 256, 0, stream>>>(z2, scale2, shift2, h,
                                                          (l < NL - 1) ? 1 : 0);
  }

  hipMemsetAsync(xpool, 0, (size_t)NG * 64 * 4, stream);
  pool_k<<<NN / 16, 256, 0, stream>>>(h, batch, xpool);
}

// Round 2
// 1247.725 us; speedup vs baseline: 3.4141x; 3.4141x over previous
//
#include <hip/hip_runtime.h>
#include <cstdint>
#include <cstddef>

#define NN 100000
#define NE 800000
#define NG 256
#define NL 5
#define EPS 1e-5f

// ---------------- init: h = atom_emb[x] ----------------
__global__ __launch_bounds__(256) void init_h_k(const int* __restrict__ x,
                                                const float* __restrict__ atom_emb,
                                                float* __restrict__ h) {
  int i = blockIdx.x * 256 + threadIdx.x;       // over NN*16 float4 slots
  if (i >= NN * 16) return;
  int n = i >> 4, c4 = i & 15;
  float4 v = *(const float4*)(atom_emb + (size_t)x[n] * 64 + c4 * 4);
  *(float4*)(h + (size_t)n * 64 + c4 * 4) = v;
}

// ---------------- CSR build ----------------
__global__ __launch_bounds__(256) void hist_k(const int* __restrict__ ei,
                                              int* __restrict__ cnt) {
  int e = blockIdx.x * 256 + threadIdx.x;
  if (e >= NE) return;
  atomicAdd(&cnt[ei[NE + e]], 1);
}

// block exclusive scan: 98 blocks x 1024 elems
__global__ __launch_bounds__(256) void scan1_k(const int* __restrict__ cnt,
                                               int* __restrict__ rs,
                                               int* __restrict__ bsum) {
  __shared__ int sh[256];
  int t = threadIdx.x;
  int base = blockIdx.x * 1024 + t * 4;
  int v0 = 0, v1 = 0, v2 = 0, v3 = 0;
  if (base + 0 < NN) v0 = cnt[base + 0];
  if (base + 1 < NN) v1 = cnt[base + 1];
  if (base + 2 < NN) v2 = cnt[base + 2];
  if (base + 3 < NN) v3 = cnt[base + 3];
  int tsum = v0 + v1 + v2 + v3;
  sh[t] = tsum;
  __syncthreads();
  for (int off = 1; off < 256; off <<= 1) {
    int x = (t >= off) ? sh[t - off] : 0;
    __syncthreads();
    sh[t] += x;
    __syncthreads();
  }
  int excl = sh[t] - tsum;
  if (base + 0 < NN) rs[base + 0] = excl;
  if (base + 1 < NN) rs[base + 1] = excl + v0;
  if (base + 2 < NN) rs[base + 2] = excl + v0 + v1;
  if (base + 3 < NN) rs[base + 3] = excl + v0 + v1 + v2;
  if (t == 255) bsum[blockIdx.x] = sh[255];
}

__global__ void scan2_k(const int* __restrict__ bsum, int* __restrict__ bofs, int nb) {
  if (threadIdx.x == 0 && blockIdx.x == 0) {
    int run = 0;
    for (int i = 0; i < nb; ++i) { bofs[i] = run; run += bsum[i]; }
  }
}

__global__ __launch_bounds__(256) void scan3_k(int* __restrict__ rs,
                                               const int* __restrict__ bofs,
                                               int* __restrict__ cursor) {
  int i = blockIdx.x * 256 + threadIdx.x;
  if (i < NN) {
    int v = rs[i] + bofs[i >> 10];
    rs[i] = v;
    cursor[i] = v;
  }
  if (i == 0) rs[NN] = NE;
}

__global__ __launch_bounds__(256) void scatter_k(const int* __restrict__ ei,
                                                 const int* __restrict__ eattr,
                                                 int* __restrict__ cursor,
                                                 int* __restrict__ epack) {
  int e = blockIdx.x * 256 + threadIdx.x;
  if (e >= NE) return;
  int d = ei[NE + e];
  int slot = atomicAdd(&cursor[d], 1);
  epack[slot] = (ei[e] << 3) | eattr[e];
}

// ---------------- per-layer: z[d] = h[d] + sum_{e:dst=d} relu(h[src]+bond[b]) ----------------
__global__ __launch_bounds__(256) void csr_aggr_k(const int* __restrict__ rowstart,
                                                  const int* __restrict__ epack,
                                                  const float* __restrict__ bond,
                                                  const float* __restrict__ h,
                                                  float* __restrict__ z) {
  int w = blockIdx.x * 4 + (threadIdx.x >> 6);   // one wave per dst row; 25000*4 == NN
  int lane = threadIdx.x & 63;
  if (w >= NN) return;
  float b0 = bond[lane], b1 = bond[64 + lane], b2 = bond[128 + lane],
        b3 = bond[192 + lane], b4 = bond[256 + lane];
  int s = rowstart[w];
  int e = rowstart[w + 1];
  float acc = h[(size_t)w * 64 + lane];
  for (int base = s; base < e; base += 64) {
    int m = e - base; if (m > 64) m = 64;
    int pk = 0;
    if (lane < m) pk = epack[base + lane];
    for (int i = 0; i < m; ++i) {
      int p = __shfl(pk, i);
      int src = p >> 3, bb = p & 7;
      float bv = bb == 0 ? b0 : bb == 1 ? b1 : bb == 2 ? b2 : bb == 3 ? b3 : b4;
      acc += fmaxf(h[(size_t)src * 64 + lane] + bv, 0.f);
    }
  }
  z[(size_t)w * 64 + lane] = acc;
}

// ---------------- gemm1: z1 = z @ W1 + b1   (K=64 -> 128 cols) ----------------
__global__ __launch_bounds__(256) void gemm1_k(const float* __restrict__ z,
                                               const float* __restrict__ W,
                                               const float* __restrict__ bias,
                                               float* __restrict__ z1) {
  __shared__ float Ws[64 * 128];   // 32 KB
  __shared__ float Xs[32][72];
  int tid = threadIdx.x;
  for (int j = tid; j < 64 * 128 / 4; j += 256)
    ((float4*)Ws)[j] = ((const float4*)W)[j];
  int row0 = blockIdx.x * 32;
  for (int j = tid; j < 32 * 16; j += 256) {
    int r = j >> 4, c4 = j & 15;
    size_t n = (size_t)row0 + r;
    *(float4*)&Xs[r][c4 * 4] = *(const float4*)(z + n * 64 + c4 * 4);
  }
  __syncthreads();
  int c0 = (tid & 15) * 8;
  int r0 = (tid >> 4) * 2;
  float acc0[8], acc1[8];
#pragma unroll
  for (int j = 0; j < 8; ++j) { acc0[j] = 0.f; acc1[j] = 0.f; }
#pragma unroll 4
  for (int k = 0; k < 64; ++k) {
    float a0 = Xs[r0][k];
    float a1 = Xs[r0 + 1][k];
    const float* wr = &Ws[k * 128 + c0];
    float4 w0 = *(const float4*)(wr);
    float4 w1 = *(const float4*)(wr + 4);
    float w[8] = {w0.x, w0.y, w0.z, w0.w, w1.x, w1.y, w1.z, w1.w};
#pragma unroll
    for (int j = 0; j < 8; ++j) {
      acc0[j] = fmaf(a0, w[j], acc0[j]);
      acc1[j] = fmaf(a1, w[j], acc1[j]);
    }
  }
  float4 bb0 = *(const float4*)(bias + c0);
  float4 bb1 = *(const float4*)(bias + c0 + 4);
  float bb[8] = {bb0.x, bb0.y, bb0.z, bb0.w, bb1.x, bb1.y, bb1.z, bb1.w};
#pragma unroll
  for (int rr = 0; rr < 2; ++rr) {
    size_t n = (size_t)row0 + r0 + rr;
    float* zp = z1 + n * 128 + c0;
    float* a = rr == 0 ? acc0 : acc1;
    *(float4*)(zp)     = make_float4(a[0] + bb[0], a[1] + bb[1], a[2] + bb[2], a[3] + bb[3]);
    *(float4*)(zp + 4) = make_float4(a[4] + bb[4], a[5] + bb[5], a[6] + bb[6], a[7] + bb[7]);
  }
}

// ---------------- column stats (sum, sumsq) in f64 ----------------
template <int C>
__global__ __launch_bounds__(256) void col_stats_k(const float* __restrict__ z,
                                                   double* __restrict__ stats) {
  const int RPB = 256 / C;
  int tid = threadIdx.x;
  int c = tid % C;
  int rw = tid / C;
  double s = 0.0, s2 = 0.0;
  for (int r = blockIdx.x * RPB + rw; r < NN; r += gridDim.x * RPB) {
    float v = z[(size_t)r * C + c];
    s += (double)v;
    s2 += (double)v * (double)v;
  }
  __shared__ double sh[2][256];
  sh[0][tid] = s; sh[1][tid] = s2;
  __syncthreads();
  for (int off = 128; off >= C; off >>= 1) {
    if (tid < off) { sh[0][tid] += sh[0][tid + off]; sh[1][tid] += sh[1][tid + off]; }
    __syncthreads();
  }
  if (tid < C) {
    atomicAdd(&stats[c], sh[0][tid]);
    atomicAdd(&stats[C + c], sh[1][tid]);
  }
}

// ---------------- finalize BN -> per-column scale/shift ----------------
__global__ void finalize_bn_k(const double* __restrict__ stats,
                              const float* __restrict__ g,
                              const float* __restrict__ be,
                              float* __restrict__ scale,
                              float* __restrict__ shift, int C) {
  int c = threadIdx.x;
  if (c < C) {
    double mean = stats[c] * (1.0 / NN);
    double var = stats[C + c] * (1.0 / NN) - mean * mean;
    float sc = g[c] * rsqrtf((float)var + EPS);
    scale[c] = sc;
    shift[c] = be[c] - (float)mean * sc;
  }
}

// ---------------- gemm2: z2 = relu(z1*scale+shift) @ W2 + b2  (K=128 -> 64 cols) ----------------
__global__ __launch_bounds__(256) void gemm2_k(const float* __restrict__ z1,
                                               const float* __restrict__ scale,
                                               const float* __restrict__ shift,
                                               const float* __restrict__ W,
                                               const float* __restrict__ bias,
                                               float* __restrict__ z2) {
  __shared__ float Ws[128 * 64];   // 32 KB
  __shared__ float Xs[32][132];
  int tid = threadIdx.x;
  for (int j = tid; j < 128 * 64 / 4; j += 256)
    ((float4*)Ws)[j] = ((const float4*)W)[j];
  int row0 = blockIdx.x * 32;
  for (int j = tid; j < 32 * 32; j += 256) {
    int r = j >> 5, c4 = j & 31;
    size_t n = (size_t)row0 + r;
    float4 v = *(const float4*)(z1 + n * 128 + c4 * 4);
    float4 sc = *(const float4*)(scale + c4 * 4);
    float4 sf = *(const float4*)(shift + c4 * 4);
    v.x = fmaxf(fmaf(v.x, sc.x, sf.x), 0.f);
    v.y = fmaxf(fmaf(v.y, sc.y, sf.y), 0.f);
    v.z = fmaxf(fmaf(v.z, sc.z, sf.z), 0.f);
    v.w = fmaxf(fmaf(v.w, sc.w, sf.w), 0.f);
    *(float4*)&Xs[r][c4 * 4] = v;
  }
  __syncthreads();
  int c0 = (tid & 7) * 8;
  int r = tid >> 3;
  float acc[8];
#pragma unroll
  for (int j = 0; j < 8; ++j) acc[j] = 0.f;
#pragma unroll 4
  for (int k = 0; k < 128; ++k) {
    float a = Xs[r][k];
    const float* wr = &Ws[k * 64 + c0];
    float4 w0 = *(const float4*)(wr);
    float4 w1 = *(const float4*)(wr + 4);
    float w[8] = {w0.x, w0.y, w0.z, w0.w, w1.x, w1.y, w1.z, w1.w};
#pragma unroll
    for (int j = 0; j < 8; ++j) acc[j] = fmaf(a, w[j], acc[j]);
  }
  float4 bb0 = *(const float4*)(bias + c0);
  float4 bb1 = *(const float4*)(bias + c0 + 4);
  size_t n = (size_t)row0 + r;
  float* zp = z2 + n * 64 + c0;
  *(float4*)(zp)     = make_float4(acc[0] + bb0.x, acc[1] + bb0.y, acc[2] + bb0.z, acc[3] + bb0.w);
  *(float4*)(zp + 4) = make_float4(acc[4] + bb1.x, acc[5] + bb1.y, acc[6] + bb1.z, acc[7] + bb1.w);
}

// ---------------- apply BN2 (+optional relu) -> h ----------------
__global__ __launch_bounds__(256) void bn_apply_k(const float* __restrict__ z2,
                                                  const float* __restrict__ scale,
                                                  const float* __restrict__ shift,
                                                  float* __restrict__ h, int do_relu) {
  int i = blockIdx.x * 256 + threadIdx.x;       // over NN*16
  if (i >= NN * 16) return;
  int c4 = i & 15;
  float4 v = ((const float4*)z2)[i];
  float4 sc = *(const float4*)(scale + c4 * 4);
  float4 sf = *(const float4*)(shift + c4 * 4);
  v.x = fmaf(v.x, sc.x, sf.x);
  v.y = fmaf(v.y, sc.y, sf.y);
  v.z = fmaf(v.z, sc.z, sf.z);
  v.w = fmaf(v.w, sc.w, sf.w);
  if (do_relu) {
    v.x = fmaxf(v.x, 0.f); v.y = fmaxf(v.y, 0.f);
    v.z = fmaxf(v.z, 0.f); v.w = fmaxf(v.w, 0.f);
  }
  ((float4*)h)[i] = v;
}

// ---------------- pool: xpool[batch[n]] += h[n]  (batch sorted) ----------------
__global__ __launch_bounds__(256) void pool_k(const float* __restrict__ h,
                                              const int* __restrict__ batch,
                                              float* __restrict__ xpool) {
  int n0 = blockIdx.x * 16;
  int tid = threadIdx.x;
  int r = tid >> 4, c4 = tid & 15;
  int n = n0 + r;
  float4 v = *(const float4*)(h + (size_t)n * 64 + c4 * 4);
  __shared__ int gfirst, gsame;
  __shared__ float red[16][64];
  if (tid == 0) {
    gfirst = batch[n0];
    gsame = (batch[n0] == batch[n0 + 15]) ? 1 : 0;
  }
  *(float4*)&red[r][c4 * 4] = v;
  __syncthreads();
  if (gsame) {
#pragma unroll
    for (int off = 8; off >= 1; off >>= 1) {
      if (r < off) {
        float4 a = *(float4*)&red[r][c4 * 4];
        float4 b = *(float4*)&red[r + off][c4 * 4];
        *(float4*)&red[r][c4 * 4] = make_float4(a.x + b.x, a.y + b.y, a.z + b.z, a.w + b.w);
      }
      __syncthreads();
    }
    if (r == 0) {
      float* p = xpool + (size_t)gfirst * 64 + c4 * 4;
      float4 a = *(float4*)&red[0][c4 * 4];
      atomicAdd(p + 0, a.x); atomicAdd(p + 1, a.y);
      atomicAdd(p + 2, a.z); atomicAdd(p + 3, a.w);
    }
  } else {
    int g = batch[n];
    float* p = xpool + (size_t)g * 64 + c4 * 4;
    atomicAdd(p + 0, v.x); atomicAdd(p + 1, v.y);
    atomicAdd(p + 2, v.z); atomicAdd(p + 3, v.w);
  }
}

extern "C" void kernel_launch(void* const* d_in, const int* in_sizes, int n_in,
                              void* d_out, int out_size, void* d_ws, size_t ws_size,
                              hipStream_t stream) {
  const int* batch = (const int*)d_in[0];
  const int* x = (const int*)d_in[1];
  const int* ei = (const int*)d_in[2];
  const int* eattr = (const int*)d_in[3];
  const float* atom_emb = (const float*)d_in[4];
  const float* bond_emb = (const float*)d_in[5];
  const float* W1 = (const float*)d_in[6];
  const float* b1 = (const float*)d_in[7];
  const float* g1 = (const float*)d_in[8];
  const float* be1 = (const float*)d_in[9];
  const float* W2 = (const float*)d_in[10];
  const float* b2 = (const float*)d_in[11];
  const float* gbn = (const float*)d_in[12];
  const float* bbn = (const float*)d_in[13];

  float* out = (float*)d_out;
  float* xpool = out;              // 256*64
  float* h = out + NG * 64;        // N*64, final h lives directly in output

  char* ws = (char*)d_ws;
  float* zsum = (float*)ws;                          // N*64 f32 = 25.6 MB (z = h+aggr; also z2)
  float* z1 = (float*)(ws + (size_t)25600000);       // N*128 f32 = 51.2 MB
  double* stat1 = (double*)(ws + (size_t)76800000);  // 256 doubles
  double* stat2 = stat1 + 256;                       // 128 doubles
  float* ssbuf = (float*)(ws + (size_t)76800000 + 3072);
  float* scale1 = ssbuf, *shift1 = ssbuf + 128;
  float* scale2 = ssbuf + 256, *shift2 = ssbuf + 320;
  int* rowstart = (int*)(ws + (size_t)76804608);     // (NN+1) ints = 400004 B
  int* epack = (int*)(ws + (size_t)77204992);        // NE ints = 3.2 MB -> ends ~80.4 MB
  // build-time temporaries alias z1 (dead until first gemm1)
  int* cnt = (int*)z1;                               // NN ints
  int* cursor = (int*)(ws + (size_t)25600000 + 512 * 1024);  // NN ints
  int* bsum = (int*)(ws + (size_t)25600000 + 1024 * 1024);   // 98 ints
  int* bofs = bsum + 128;
  float* z2 = zsum;

  init_h_k<<<(NN * 16 + 255) / 256, 256, 0, stream>>>(x, atom_emb, h);

  // ---- CSR build (edge structure shared by all layers) ----
  hipMemsetAsync(cnt, 0, (size_t)NN * 4, stream);
  hist_k<<<(NE + 255) / 256, 256, 0, stream>>>(ei, cnt);
  scan1_k<<<98, 256, 0, stream>>>(cnt, rowstart, bsum);
  scan2_k<<<1, 64, 0, stream>>>(bsum, bofs, 98);
  scan3_k<<<(NN + 255) / 256, 256, 0, stream>>>(rowstart, bofs, cursor);
  scatter_k<<<(NE + 255) / 256, 256, 0, stream>>>(ei, eattr, cursor, epack);

  for (int l = 0; l < NL; ++l) {
    hipMemsetAsync(stat1, 0, 3072, stream);
    csr_aggr_k<<<NN / 4, 256, 0, stream>>>(rowstart, epack, bond_emb, h, zsum);
    gemm1_k<<<NN / 32, 256, 0, stream>>>(zsum, W1 + (size_t)l * 64 * 128,
                                         b1 + (size_t)l * 128, z1);
    col_stats_k<128><<<1024, 256, 0, stream>>>(z1, stat1);
    finalize_bn_k<<<1, 128, 0, stream>>>(stat1, g1 + (size_t)l * 128, be1 + (size_t)l * 128,
                                         scale1, shift1, 128);
    gemm2_k<<<NN / 32, 256, 0, stream>>>(z1, scale1, shift1, W2 + (size_t)l * 128 * 64,
                                         b2 + (size_t)l * 64, z2);
    col_stats_k<64><<<1024, 256, 0, stream>>>(z2, stat2);
    finalize_bn_k<<<1, 64, 0, stream>>>(stat2, gbn + (size_t)l * 64, bbn + (size_t)l * 64,
                                        scale2, shift2, 64);
    bn_apply_k<<<(NN * 16 + 255) / 256, 256, 0, stream>>>(z2, scale2, shift2, h,
                                                          (l < NL - 1) ? 1 : 0);
  }

  hipMemsetAsync(xpool, 0, (size_t)NG * 64 * 4, stream);
  pool_k<<<NN / 16, 256, 0, stream>>>(h, batch, xpool);
}

// Round 3
// 738.118 us; speedup vs baseline: 5.7713x; 1.6904x over previous
//
#include <hip/hip_runtime.h>
#include <cstdint>
#include <cstddef>

#define NN 100000
#define NP 100032
#define NE 800000
#define NG 256
#define NL 5
#define EPS 1e-5f

typedef __bf16 bf16x8 __attribute__((ext_vector_type(8)));
typedef float f32x4 __attribute__((ext_vector_type(4)));

__device__ __forceinline__ float bf2f(unsigned short u) {
  union { unsigned int i; float f; } x; x.i = ((unsigned int)u) << 16; return x.f;
}
__device__ __forceinline__ unsigned short f2bf(float f) {
  union { float f; unsigned int i; } x; x.f = f;
  unsigned int r = x.i + 0x7fffu + ((x.i >> 16) & 1u);
  return (unsigned short)(r >> 16);
}

// ---------------- init: hb = bf16(atom_emb[x]) ----------------
__global__ __launch_bounds__(256) void init_h_k(const int* __restrict__ x,
                                                const float* __restrict__ atom_emb,
                                                unsigned short* __restrict__ hb) {
  int i = blockIdx.x * 256 + threadIdx.x;   // NN*8 exactly
  int n = i >> 3, c0 = (i & 7) * 8;
  const float* p = atom_emb + (size_t)x[n] * 64 + c0;
  float4 v0 = *(const float4*)p;
  float4 v1 = *(const float4*)(p + 4);
  union { bf16x8 b; unsigned short u[8]; } o;
  o.u[0] = f2bf(v0.x); o.u[1] = f2bf(v0.y); o.u[2] = f2bf(v0.z); o.u[3] = f2bf(v0.w);
  o.u[4] = f2bf(v1.x); o.u[5] = f2bf(v1.y); o.u[6] = f2bf(v1.z); o.u[7] = f2bf(v1.w);
  *(bf16x8*)(hb + (size_t)n * 64 + c0) = o.b;
}

// ---------------- weight transpose+convert: Wt[l][col][k] = bf16(W[l][k][col]) ----------------
__global__ __launch_bounds__(256) void wconv_k(const float* __restrict__ W1,
                                               const float* __restrict__ W2,
                                               unsigned short* __restrict__ Wt1,
                                               unsigned short* __restrict__ Wt2) {
  int i = blockIdx.x * 256 + threadIdx.x;
  const int S = NL * 128 * 64;   // 40960
  if (i < S) {
    int l = i / (128 * 64), r = i % (128 * 64);
    int c = r / 64, k = r % 64;
    Wt1[i] = f2bf(W1[(size_t)l * 64 * 128 + (size_t)k * 128 + c]);
  } else if (i < 2 * S) {
    int j = i - S;
    int l = j / (128 * 64), r = j % (128 * 64);
    int c = r / 128, k = r % 128;
    Wt2[j] = f2bf(W2[(size_t)l * 128 * 64 + (size_t)k * 64 + c]);
  }
}

// ---------------- CSR build ----------------
__global__ __launch_bounds__(256) void hist_k(const int* __restrict__ ei,
                                              int* __restrict__ cnt) {
  int e = blockIdx.x * 256 + threadIdx.x;
  if (e >= NE) return;
  atomicAdd(&cnt[ei[NE + e]], 1);
}

__global__ __launch_bounds__(256) void scan1_k(const int* __restrict__ cnt,
                                               int* __restrict__ rs,
                                               int* __restrict__ bsum) {
  __shared__ int sh[256];
  int t = threadIdx.x;
  int base = blockIdx.x * 1024 + t * 4;
  int v0 = 0, v1 = 0, v2 = 0, v3 = 0;
  if (base + 0 < NN) v0 = cnt[base + 0];
  if (base + 1 < NN) v1 = cnt[base + 1];
  if (base + 2 < NN) v2 = cnt[base + 2];
  if (base + 3 < NN) v3 = cnt[base + 3];
  int tsum = v0 + v1 + v2 + v3;
  sh[t] = tsum;
  __syncthreads();
  for (int off = 1; off < 256; off <<= 1) {
    int x = (t >= off) ? sh[t - off] : 0;
    __syncthreads();
    sh[t] += x;
    __syncthreads();
  }
  int excl = sh[t] - tsum;
  if (base + 0 < NN) rs[base + 0] = excl;
  if (base + 1 < NN) rs[base + 1] = excl + v0;
  if (base + 2 < NN) rs[base + 2] = excl + v0 + v1;
  if (base + 3 < NN) rs[base + 3] = excl + v0 + v1 + v2;
  if (t == 255) bsum[blockIdx.x] = sh[255];
}

__global__ void scan2_k(const int* __restrict__ bsum, int* __restrict__ bofs, int nb) {
  if (threadIdx.x == 0 && blockIdx.x == 0) {
    int run = 0;
    for (int i = 0; i < nb; ++i) { bofs[i] = run; run += bsum[i]; }
  }
}

__global__ __launch_bounds__(256) void scan3_k(int* __restrict__ rs,
                                               const int* __restrict__ bofs,
                                               int* __restrict__ cursor) {
  int i = blockIdx.x * 256 + threadIdx.x;
  if (i < NN) {
    int v = rs[i] + bofs[i >> 10];
    rs[i] = v;
    cursor[i] = v;
  }
  if (i == 0) rs[NN] = NE;
}

__global__ __launch_bounds__(256) void scatter_k(const int* __restrict__ ei,
                                                 const int* __restrict__ eattr,
                                                 int* __restrict__ cursor,
                                                 int* __restrict__ epack) {
  int e = blockIdx.x * 256 + threadIdx.x;
  if (e >= NE) return;
  int d = ei[NE + e];
  int slot = atomicAdd(&cursor[d], 1);
  epack[slot] = (ei[e] << 3) | eattr[e];
}

// ---------------- z[d] = h[d] + sum relu(h[src]+bond[b])  (bf16 in/out, f32 accum) ----------------
__global__ __launch_bounds__(256) void csr_aggr_k(const int* __restrict__ rowstart,
                                                  const int* __restrict__ epack,
                                                  const float* __restrict__ bond,
                                                  const unsigned short* __restrict__ hb,
                                                  unsigned short* __restrict__ zb) {
  int w = blockIdx.x * 4 + (threadIdx.x >> 6);   // one wave per dst row
  int lane = threadIdx.x & 63;
  float b0 = bond[lane], b1 = bond[64 + lane], b2 = bond[128 + lane],
        b3 = bond[192 + lane], b4 = bond[256 + lane];
  int s = rowstart[w];
  int e = rowstart[w + 1];
  float acc = bf2f(hb[(size_t)w * 64 + lane]);
  for (int base = s; base < e; base += 64) {
    int m = e - base; if (m > 64) m = 64;
    int pk = (lane < m) ? epack[base + lane] : 0;
    int i = 0;
    for (; i + 2 <= m; i += 2) {
      int p0 = __shfl(pk, i), p1 = __shfl(pk, i + 1);
      float u0 = bf2f(hb[(size_t)(p0 >> 3) * 64 + lane]);
      float u1 = bf2f(hb[(size_t)(p1 >> 3) * 64 + lane]);
      int q0 = p0 & 7, q1 = p1 & 7;
      float bv0 = q0 == 0 ? b0 : q0 == 1 ? b1 : q0 == 2 ? b2 : q0 == 3 ? b3 : b4;
      float bv1 = q1 == 0 ? b0 : q1 == 1 ? b1 : q1 == 2 ? b2 : q1 == 3 ? b3 : b4;
      acc += fmaxf(u0 + bv0, 0.f);
      acc += fmaxf(u1 + bv1, 0.f);
    }
    if (i < m) {
      int p0 = __shfl(pk, i);
      float u0 = bf2f(hb[(size_t)(p0 >> 3) * 64 + lane]);
      int q0 = p0 & 7;
      float bv0 = q0 == 0 ? b0 : q0 == 1 ? b1 : q0 == 2 ? b2 : q0 == 3 ? b3 : b4;
      acc += fmaxf(u0 + bv0, 0.f);
    }
  }
  zb[(size_t)w * 64 + lane] = f2bf(acc);
}

// ---------------- gemm1 MFMA: z1 = zb @ W1 + b1, fused col-stats ----------------
__global__ __launch_bounds__(256) void gemm1_k(const unsigned short* __restrict__ zb,
                                               const unsigned short* __restrict__ Wt,
                                               const float* __restrict__ bias,
                                               unsigned short* __restrict__ z1b,
                                               float* __restrict__ statf) {
  __shared__ float sred[256];
  int tid = threadIdx.x;
  sred[tid] = 0.f;
  int w = tid >> 6, lane = tid & 63;
  int rlo = lane & 15, khi = lane >> 4;
  int row0 = blockIdx.x * 64 + w * 16;
  const bf16x8* ap = (const bf16x8*)(zb + (size_t)(row0 + rlo) * 64 + khi * 8);
  bf16x8 a0 = ap[0];
  bf16x8 a1 = ap[4];   // +32 elements
  __syncthreads();
#pragma unroll
  for (int ct = 0; ct < 8; ++ct) {
    const bf16x8* bp = (const bf16x8*)(Wt + ((size_t)(ct * 16 + rlo) * 64 + khi * 8));
    f32x4 acc;
    acc[0] = 0.f; acc[1] = 0.f; acc[2] = 0.f; acc[3] = 0.f;
    acc = __builtin_amdgcn_mfma_f32_16x16x32_bf16(a0, bp[0], acc, 0, 0, 0);
    acc = __builtin_amdgcn_mfma_f32_16x16x32_bf16(a1, bp[4], acc, 0, 0, 0);
    int c = ct * 16 + rlo;
    float bs = bias[c];
    float s = 0.f, s2 = 0.f;
#pragma unroll
    for (int q = 0; q < 4; ++q) {
      int row = row0 + khi * 4 + q;
      float v = acc[q] + bs;
      unsigned short ub = f2bf(v);
      z1b[(size_t)row * 128 + c] = ub;
      float vf = bf2f(ub);
      if (row < NN) { s += vf; s2 += vf * vf; }
    }
    atomicAdd(&sred[c], s);
    atomicAdd(&sred[128 + c], s2);
  }
  __syncthreads();
  atomicAdd(&statf[(blockIdx.x & 7) * 256 + tid], sred[tid]);
}

// ---------------- gemm2 MFMA: z2 = relu(bn1(z1)) @ W2 + b2, BN1 finalize in prologue, fused stats ----------------
__global__ __launch_bounds__(256) void gemm2_k(const unsigned short* __restrict__ z1b,
                                               const unsigned short* __restrict__ Wt,
                                               const float* __restrict__ bias,
                                               const float* __restrict__ g,
                                               const float* __restrict__ be,
                                               const float* __restrict__ stat1f,
                                               unsigned short* __restrict__ z2b,
                                               float* __restrict__ stat2f) {
  __shared__ float scl[128], shf[128], sred[128];
  int tid = threadIdx.x;
  if (tid < 128) {
    float s = 0.f, s2 = 0.f;
#pragma unroll
    for (int r = 0; r < 8; ++r) { s += stat1f[r * 256 + tid]; s2 += stat1f[r * 256 + 128 + tid]; }
    float mean = s * (1.f / NN);
    float var = fmaxf(s2 * (1.f / NN) - mean * mean, 0.f);
    float sc = g[tid] * rsqrtf(var + EPS);
    scl[tid] = sc;
    shf[tid] = be[tid] - mean * sc;
    sred[tid] = 0.f;
  }
  __syncthreads();
  int w = tid >> 6, lane = tid & 63;
  int rlo = lane & 15, khi = lane >> 4;
  int row0 = blockIdx.x * 64 + w * 16;
  const unsigned short* zr = z1b + (size_t)(row0 + rlo) * 128;
  f32x4 acc[4];
#pragma unroll
  for (int ct = 0; ct < 4; ++ct) { acc[ct][0] = 0.f; acc[ct][1] = 0.f; acc[ct][2] = 0.f; acc[ct][3] = 0.f; }
#pragma unroll
  for (int kc = 0; kc < 4; ++kc) {
    int k0 = kc * 32 + khi * 8;
    union { bf16x8 b; unsigned short u[8]; } raw, af;
    raw.b = *(const bf16x8*)(zr + k0);
#pragma unroll
    for (int j = 0; j < 8; ++j) {
      float vf = fmaf(bf2f(raw.u[j]), scl[k0 + j], shf[k0 + j]);
      af.u[j] = f2bf(fmaxf(vf, 0.f));
    }
#pragma unroll
    for (int ct = 0; ct < 4; ++ct) {
      const bf16x8* bp = (const bf16x8*)(Wt + ((size_t)(ct * 16 + rlo) * 128 + k0));
      acc[ct] = __builtin_amdgcn_mfma_f32_16x16x32_bf16(af.b, bp[0], acc[ct], 0, 0, 0);
    }
  }
#pragma unroll
  for (int ct = 0; ct < 4; ++ct) {
    int c = ct * 16 + rlo;
    float bs = bias[c];
    float s = 0.f, s2 = 0.f;
#pragma unroll
    for (int q = 0; q < 4; ++q) {
      int row = row0 + khi * 4 + q;
      float v = acc[ct][q] + bs;
      unsigned short ub = f2bf(v);
      z2b[(size_t)row * 64 + c] = ub;
      float vf = bf2f(ub);
      if (row < NN) { s += vf; s2 += vf * vf; }
    }
    atomicAdd(&sred[c], s);
    atomicAdd(&sred[64 + c], s2);
  }
  __syncthreads();
  if (tid < 128) atomicAdd(&stat2f[(blockIdx.x & 7) * 128 + tid], sred[tid]);
}

// ---------------- bn2 apply (+relu), BN2 finalize in prologue ----------------
__global__ __launch_bounds__(256) void bn_apply_k(const unsigned short* __restrict__ z2b,
                                                  const float* __restrict__ stat2f,
                                                  const float* __restrict__ g,
                                                  const float* __restrict__ be,
                                                  unsigned short* __restrict__ hb,
                                                  float* __restrict__ hf,
                                                  int final_layer) {
  __shared__ float scl[64], shf[64];
  int tid = threadIdx.x;
  if (tid < 64) {
    float s = 0.f, s2 = 0.f;
#pragma unroll
    for (int r = 0; r < 8; ++r) { s += stat2f[r * 128 + tid]; s2 += stat2f[r * 128 + 64 + tid]; }
    float mean = s * (1.f / NN);
    float var = fmaxf(s2 * (1.f / NN) - mean * mean, 0.f);
    float sc = g[tid] * rsqrtf(var + EPS);
    scl[tid] = sc;
    shf[tid] = be[tid] - mean * sc;
  }
  __syncthreads();
  int i = blockIdx.x * 256 + tid;   // NN*8 exactly
  int n = i >> 3, c0 = (i & 7) * 8;
  union { bf16x8 b; unsigned short u[8]; } raw;
  raw.b = *(const bf16x8*)(z2b + (size_t)n * 64 + c0);
  float v[8];
#pragma unroll
  for (int j = 0; j < 8; ++j) v[j] = fmaf(bf2f(raw.u[j]), scl[c0 + j], shf[c0 + j]);
  if (final_layer) {
    float* p = hf + (size_t)n * 64 + c0;
    *(float4*)(p)     = make_float4(v[0], v[1], v[2], v[3]);
    *(float4*)(p + 4) = make_float4(v[4], v[5], v[6], v[7]);
  } else {
    union { bf16x8 b; unsigned short u[8]; } o;
#pragma unroll
    for (int j = 0; j < 8; ++j) o.u[j] = f2bf(fmaxf(v[j], 0.f));
    *(bf16x8*)(hb + (size_t)n * 64 + c0) = o.b;
  }
}

// ---------------- pool: xpool[batch[n]] += h[n]  (batch sorted) ----------------
__global__ __launch_bounds__(256) void pool_k(const float* __restrict__ h,
                                              const int* __restrict__ batch,
                                              float* __restrict__ xpool) {
  int n0 = blockIdx.x * 16;
  int tid = threadIdx.x;
  int r = tid >> 4, c4 = tid & 15;
  int n = n0 + r;
  float4 v = *(const float4*)(h + (size_t)n * 64 + c4 * 4);
  __shared__ int gfirst, gsame;
  __shared__ float red[16][64];
  if (tid == 0) {
    gfirst = batch[n0];
    gsame = (batch[n0] == batch[n0 + 15]) ? 1 : 0;
  }
  *(float4*)&red[r][c4 * 4] = v;
  __syncthreads();
  if (gsame) {
#pragma unroll
    for (int off = 8; off >= 1; off >>= 1) {
      if (r < off) {
        float4 a = *(float4*)&red[r][c4 * 4];
        float4 b = *(float4*)&red[r + off][c4 * 4];
        *(float4*)&red[r][c4 * 4] = make_float4(a.x + b.x, a.y + b.y, a.z + b.z, a.w + b.w);
      }
      __syncthreads();
    }
    if (r == 0) {
      float* p = xpool + (size_t)gfirst * 64 + c4 * 4;
      float4 a = *(float4*)&red[0][c4 * 4];
      atomicAdd(p + 0, a.x); atomicAdd(p + 1, a.y);
      atomicAdd(p + 2, a.z); atomicAdd(p + 3, a.w);
    }
  } else {
    int g = batch[n];
    float* p = xpool + (size_t)g * 64 + c4 * 4;
    atomicAdd(p + 0, v.x); atomicAdd(p + 1, v.y);
    atomicAdd(p + 2, v.z); atomicAdd(p + 3, v.w);
  }
}

extern "C" void kernel_launch(void* const* d_in, const int* in_sizes, int n_in,
                              void* d_out, int out_size, void* d_ws, size_t ws_size,
                              hipStream_t stream) {
  const int* batch = (const int*)d_in[0];
  const int* x = (const int*)d_in[1];
  const int* ei = (const int*)d_in[2];
  const int* eattr = (const int*)d_in[3];
  const float* atom_emb = (const float*)d_in[4];
  const float* bond_emb = (const float*)d_in[5];
  const float* W1 = (const float*)d_in[6];
  const float* b1 = (const float*)d_in[7];
  const float* g1 = (const float*)d_in[8];
  const float* be1 = (const float*)d_in[9];
  const float* W2 = (const float*)d_in[10];
  const float* b2 = (const float*)d_in[11];
  const float* gbn = (const float*)d_in[12];
  const float* bbn = (const float*)d_in[13];

  float* out = (float*)d_out;
  float* xpool = out;               // 256*64
  float* hf = out + NG * 64;        // final f32 h lives directly in output

  char* ws = (char*)d_ws;
  unsigned short* hb  = (unsigned short*)(ws);                      // NP*64 bf16 = 12.80 MB
  unsigned short* zb  = (unsigned short*)(ws + 12804096);           // NP*64 bf16 (also z2b)
  unsigned short* z1b = (unsigned short*)(ws + 25608192);           // NP*128 bf16 = 25.6 MB
  float* statf        = (float*)(ws + 51216384);                    // 8*256 + 8*128 f32 = 12 KB
  float* stat1f = statf;
  float* stat2f = statf + 2048;
  unsigned short* Wt1 = (unsigned short*)(ws + 51228672);           // 5*128*64 bf16
  unsigned short* Wt2 = (unsigned short*)(ws + 51310592);           // 5*64*128 bf16
  int* rowstart       = (int*)(ws + 51392512);                      // NN+1 ints
  int* epack          = (int*)(ws + 51792520);                      // NE ints
  // CSR build temporaries alias z1b region (dead until first gemm1)
  int* cnt    = (int*)(ws + 25608192);
  int* cursor = (int*)(ws + 25608192 + 1048576);
  int* bsum   = (int*)(ws + 25608192 + 2097152);
  int* bofs   = bsum + 128;
  unsigned short* z2b = zb;

  init_h_k<<<NN * 8 / 256, 256, 0, stream>>>(x, atom_emb, hb);
  wconv_k<<<(2 * NL * 128 * 64 + 255) / 256, 256, 0, stream>>>(W1, W2, Wt1, Wt2);

  // ---- CSR build (edge structure shared by all layers) ----
  hipMemsetAsync(cnt, 0, (size_t)NN * 4, stream);
  hist_k<<<(NE + 255) / 256, 256, 0, stream>>>(ei, cnt);
  scan1_k<<<98, 256, 0, stream>>>(cnt, rowstart, bsum);
  scan2_k<<<1, 64, 0, stream>>>(bsum, bofs, 98);
  scan3_k<<<(NN + 255) / 256, 256, 0, stream>>>(rowstart, bofs, cursor);
  scatter_k<<<(NE + 255) / 256, 256, 0, stream>>>(ei, eattr, cursor, epack);

  for (int l = 0; l < NL; ++l) {
    hipMemsetAsync(statf, 0, 12288, stream);
    csr_aggr_k<<<NN / 4, 256, 0, stream>>>(rowstart, epack, bond_emb, hb, zb);
    gemm1_k<<<(NN + 63) / 64, 256, 0, stream>>>(zb, Wt1 + (size_t)l * 128 * 64,
                                                b1 + (size_t)l * 128, z1b, stat1f);
    gemm2_k<<<(NN + 63) / 64, 256, 0, stream>>>(z1b, Wt2 + (size_t)l * 64 * 128,
                                                b2 + (size_t)l * 64,
                                                g1 + (size_t)l * 128, be1 + (size_t)l * 128,
                                                stat1f, z2b, stat2f);
    bn_apply_k<<<NN * 8 / 256, 256, 0, stream>>>(z2b, stat2f,
                                                 gbn + (size_t)l * 64, bbn + (size_t)l * 64,
                                                 hb, hf, (l == NL - 1) ? 1 : 0);
  }

  hipMemsetAsync(xpool, 0, (size_t)NG * 64 * 4, stream);
  pool_k<<<NN / 16, 256, 0, stream>>>(hf, batch, xpool);
}

// Round 4
// 728.279 us; speedup vs baseline: 5.8493x; 1.0135x over previous
//
#include <hip/hip_runtime.h>
#include <cstdint>
#include <cstddef>

#define NN 100000
#define NP 100032
#define NE 800000
#define NG 256
#define NL 5
#define EPS 1e-5f

typedef __bf16 bf16x8 __attribute__((ext_vector_type(8)));
typedef float f32x4 __attribute__((ext_vector_type(4)));

__device__ __forceinline__ float bf2f(unsigned short u) {
  union { unsigned int i; float f; } x; x.i = ((unsigned int)u) << 16; return x.f;
}
__device__ __forceinline__ unsigned short f2bf(float f) {
  union { float f; unsigned int i; } x; x.f = f;
  unsigned int r = x.i + 0x7fffu + ((x.i >> 16) & 1u);
  return (unsigned short)(r >> 16);
}

// ---------------- init: A = bf16(atom_emb[x]) ----------------
__global__ __launch_bounds__(256) void init_h_k(const int* __restrict__ x,
                                                const float* __restrict__ atom_emb,
                                                unsigned short* __restrict__ A) {
  int i = blockIdx.x * 256 + threadIdx.x;   // NN*8 exactly
  int n = i >> 3, c0 = (i & 7) * 8;
  const float* p = atom_emb + (size_t)x[n] * 64 + c0;
  float4 v0 = *(const float4*)p;
  float4 v1 = *(const float4*)(p + 4);
  union { bf16x8 b; unsigned short u[8]; } o;
  o.u[0] = f2bf(v0.x); o.u[1] = f2bf(v0.y); o.u[2] = f2bf(v0.z); o.u[3] = f2bf(v0.w);
  o.u[4] = f2bf(v1.x); o.u[5] = f2bf(v1.y); o.u[6] = f2bf(v1.z); o.u[7] = f2bf(v1.w);
  *(bf16x8*)(A + (size_t)n * 64 + c0) = o.b;
}

// ---------------- weight transpose+convert: Wt[l][col][k] = bf16(W[l][k][col]) ----------------
__global__ __launch_bounds__(256) void wconv_k(const float* __restrict__ W1,
                                               const float* __restrict__ W2,
                                               unsigned short* __restrict__ Wt1,
                                               unsigned short* __restrict__ Wt2) {
  int i = blockIdx.x * 256 + threadIdx.x;
  const int S = NL * 128 * 64;   // 40960
  if (i < S) {
    int l = i / (128 * 64), r = i % (128 * 64);
    int c = r / 64, k = r % 64;
    Wt1[i] = f2bf(W1[(size_t)l * 64 * 128 + (size_t)k * 128 + c]);
  } else if (i < 2 * S) {
    int j = i - S;
    int l = j / (128 * 64), r = j % (128 * 64);
    int c = r / 128, k = r % 128;
    Wt2[j] = f2bf(W2[(size_t)l * 128 * 64 + (size_t)k * 64 + c]);
  }
}

// ---------------- CSR build ----------------
__global__ __launch_bounds__(256) void hist_k(const int* __restrict__ ei,
                                              int* __restrict__ cnt) {
  int e = blockIdx.x * 256 + threadIdx.x;
  if (e >= NE) return;
  atomicAdd(&cnt[ei[NE + e]], 1);
}

__global__ __launch_bounds__(256) void scan1_k(const int* __restrict__ cnt,
                                               int* __restrict__ rs,
                                               int* __restrict__ bsum) {
  __shared__ int sh[256];
  int t = threadIdx.x;
  int base = blockIdx.x * 1024 + t * 4;
  int v0 = 0, v1 = 0, v2 = 0, v3 = 0;
  if (base + 0 < NN) v0 = cnt[base + 0];
  if (base + 1 < NN) v1 = cnt[base + 1];
  if (base + 2 < NN) v2 = cnt[base + 2];
  if (base + 3 < NN) v3 = cnt[base + 3];
  int tsum = v0 + v1 + v2 + v3;
  sh[t] = tsum;
  __syncthreads();
  for (int off = 1; off < 256; off <<= 1) {
    int x = (t >= off) ? sh[t - off] : 0;
    __syncthreads();
    sh[t] += x;
    __syncthreads();
  }
  int excl = sh[t] - tsum;
  if (base + 0 < NN) rs[base + 0] = excl;
  if (base + 1 < NN) rs[base + 1] = excl + v0;
  if (base + 2 < NN) rs[base + 2] = excl + v0 + v1;
  if (base + 3 < NN) rs[base + 3] = excl + v0 + v1 + v2;
  if (t == 255) bsum[blockIdx.x] = sh[255];
}

__global__ void scan2_k(const int* __restrict__ bsum, int* __restrict__ bofs, int nb) {
  if (threadIdx.x == 0 && blockIdx.x == 0) {
    int run = 0;
    for (int i = 0; i < nb; ++i) { bofs[i] = run; run += bsum[i]; }
  }
}

__global__ __launch_bounds__(256) void scan3_k(int* __restrict__ rs,
                                               const int* __restrict__ bofs,
                                               int* __restrict__ cursor) {
  int i = blockIdx.x * 256 + threadIdx.x;
  if (i < NN) {
    int v = rs[i] + bofs[i >> 10];
    rs[i] = v;
    cursor[i] = v;
  }
  if (i == 0) rs[NN] = NE;
}

// XCD-banded scatter: block bid&7 only writes dst band of 12500 rows, so its
// 400KB epack slice stays XCD-exclusive in L2 and stores merge into full lines.
__global__ __launch_bounds__(256) void scatter_k(const int* __restrict__ ei,
                                                 const int* __restrict__ eattr,
                                                 int* __restrict__ cursor,
                                                 int* __restrict__ epack) {
  int band = blockIdx.x & 7;
  int e = (blockIdx.x >> 3) * 256 + threadIdx.x;
  if (e >= NE) return;
  int d = ei[NE + e];
  if (d / 12500 != band) return;
  int slot = atomicAdd(&cursor[d], 1);
  epack[slot] = (ei[e] << 3) | eattr[e];
}

// ---------------- fused gather: B[w] = hsrc(w) + sum relu(hsrc(src)+bond[b]) ----------------
// hsrc(n) = MODE ? relu(A[n]*scl+shf) : A[n]   (BN of previous layer fused in)
// lane = (edge_slot es 0-3, chan_group cg 0-15): 4 edges in flight per wave issue.
template <int MODE>
__global__ __launch_bounds__(256) void csr_aggr_k(const int* __restrict__ rowstart,
                                                  const int* __restrict__ epack,
                                                  const float* __restrict__ bond,
                                                  const unsigned short* __restrict__ A,
                                                  const float* __restrict__ scl64,
                                                  const float* __restrict__ shf64,
                                                  unsigned short* __restrict__ B) {
  __shared__ float bl[320];   // bond [5][64] f32
  int tid = threadIdx.x;
  for (int j = tid; j < 320; j += 256) bl[j] = bond[j];
  __syncthreads();
  int w = blockIdx.x * 4 + (tid >> 6);
  int lane = tid & 63;
  int es = lane >> 4, cg = lane & 15, c0 = cg * 4;
  float s0 = 1.f, s1 = 1.f, s2 = 1.f, s3 = 1.f, f0 = 0.f, f1 = 0.f, f2 = 0.f, f3 = 0.f;
  if (MODE) {
    s0 = scl64[c0]; s1 = scl64[c0 + 1]; s2 = scl64[c0 + 2]; s3 = scl64[c0 + 3];
    f0 = shf64[c0]; f1 = shf64[c0 + 1]; f2 = shf64[c0 + 2]; f3 = shf64[c0 + 3];
  }
  int s = rowstart[w], e = rowstart[w + 1];
  float a0 = 0.f, a1 = 0.f, a2 = 0.f, a3 = 0.f;
  for (int base = s; base < e; base += 64) {
    int m = e - base; if (m > 64) m = 64;
    int pk = (lane < m) ? epack[base + lane] : 0;
    int iters = (m + 3) >> 2;
    for (int i = 0; i < iters; ++i) {
      int idx = i * 4 + es;
      int p = __shfl(pk, idx);
      if (idx < m) {
        ushort4 hv = *(const ushort4*)(A + (size_t)(p >> 3) * 64 + c0);
        float4 bv = *(const float4*)&bl[(p & 7) * 64 + c0];
        float v0 = bf2f(hv.x), v1 = bf2f(hv.y), v2 = bf2f(hv.z), v3 = bf2f(hv.w);
        if (MODE) {
          v0 = fmaxf(fmaf(v0, s0, f0), 0.f);
          v1 = fmaxf(fmaf(v1, s1, f1), 0.f);
          v2 = fmaxf(fmaf(v2, s2, f2), 0.f);
          v3 = fmaxf(fmaf(v3, s3, f3), 0.f);
        }
        a0 += fmaxf(v0 + bv.x, 0.f);
        a1 += fmaxf(v1 + bv.y, 0.f);
        a2 += fmaxf(v2 + bv.z, 0.f);
        a3 += fmaxf(v3 + bv.w, 0.f);
      }
    }
  }
  a0 += __shfl_xor(a0, 16); a0 += __shfl_xor(a0, 32);
  a1 += __shfl_xor(a1, 16); a1 += __shfl_xor(a1, 32);
  a2 += __shfl_xor(a2, 16); a2 += __shfl_xor(a2, 32);
  a3 += __shfl_xor(a3, 16); a3 += __shfl_xor(a3, 32);
  if (es == 0) {
    ushort4 rv = *(const ushort4*)(A + (size_t)w * 64 + c0);
    float r0 = bf2f(rv.x), r1 = bf2f(rv.y), r2 = bf2f(rv.z), r3 = bf2f(rv.w);
    if (MODE) {
      r0 = fmaxf(fmaf(r0, s0, f0), 0.f);
      r1 = fmaxf(fmaf(r1, s1, f1), 0.f);
      r2 = fmaxf(fmaf(r2, s2, f2), 0.f);
      r3 = fmaxf(fmaf(r3, s3, f3), 0.f);
    }
    ushort4 o;
    o.x = f2bf(a0 + r0); o.y = f2bf(a1 + r1);
    o.z = f2bf(a2 + r2); o.w = f2bf(a3 + r3);
    *(ushort4*)(B + (size_t)w * 64 + c0) = o;
  }
}

// ---------------- gemm1 MFMA: z1 = B @ W1 + b1, fused col-stats ----------------
__global__ __launch_bounds__(256) void gemm1_k(const unsigned short* __restrict__ zb,
                                               const unsigned short* __restrict__ Wt,
                                               const float* __restrict__ bias,
                                               unsigned short* __restrict__ z1b,
                                               float* __restrict__ statf) {
  __shared__ float sred[256];
  int tid = threadIdx.x;
  sred[tid] = 0.f;
  int w = tid >> 6, lane = tid & 63;
  int rlo = lane & 15, khi = lane >> 4;
  int row0 = blockIdx.x * 64 + w * 16;
  const bf16x8* ap = (const bf16x8*)(zb + (size_t)(row0 + rlo) * 64 + khi * 8);
  bf16x8 a0 = ap[0];
  bf16x8 a1 = ap[4];   // +32 elements
  __syncthreads();
#pragma unroll
  for (int ct = 0; ct < 8; ++ct) {
    const bf16x8* bp = (const bf16x8*)(Wt + ((size_t)(ct * 16 + rlo) * 64 + khi * 8));
    f32x4 acc;
    acc[0] = 0.f; acc[1] = 0.f; acc[2] = 0.f; acc[3] = 0.f;
    acc = __builtin_amdgcn_mfma_f32_16x16x32_bf16(a0, bp[0], acc, 0, 0, 0);
    acc = __builtin_amdgcn_mfma_f32_16x16x32_bf16(a1, bp[4], acc, 0, 0, 0);
    int c = ct * 16 + rlo;
    float bs = bias[c];
    float s = 0.f, s2 = 0.f;
#pragma unroll
    for (int q = 0; q < 4; ++q) {
      int row = row0 + khi * 4 + q;
      float v = acc[q] + bs;
      unsigned short ub = f2bf(v);
      z1b[(size_t)row * 128 + c] = ub;
      float vf = bf2f(ub);
      if (row < NN) { s += vf; s2 += vf * vf; }
    }
    atomicAdd(&sred[c], s);
    atomicAdd(&sred[128 + c], s2);
  }
  __syncthreads();
  atomicAdd(&statf[(blockIdx.x & 7) * 256 + tid], sred[tid]);
}

// ---------------- gemm2 MFMA: z2 = relu(bn1(z1)) @ W2 + b2, BN1 finalize in prologue ----------------
__global__ __launch_bounds__(256) void gemm2_k(const unsigned short* __restrict__ z1b,
                                               const unsigned short* __restrict__ Wt,
                                               const float* __restrict__ bias,
                                               const float* __restrict__ g,
                                               const float* __restrict__ be,
                                               const float* __restrict__ stat1f,
                                               unsigned short* __restrict__ z2b,
                                               float* __restrict__ stat2f) {
  __shared__ float scl[128], shf[128], sred[128];
  int tid = threadIdx.x;
  if (tid < 128) {
    float s = 0.f, s2 = 0.f;
#pragma unroll
    for (int r = 0; r < 8; ++r) { s += stat1f[r * 256 + tid]; s2 += stat1f[r * 256 + 128 + tid]; }
    float mean = s * (1.f / NN);
    float var = fmaxf(s2 * (1.f / NN) - mean * mean, 0.f);
    float sc = g[tid] * rsqrtf(var + EPS);
    scl[tid] = sc;
    shf[tid] = be[tid] - mean * sc;
    sred[tid] = 0.f;
  }
  __syncthreads();
  int w = tid >> 6, lane = tid & 63;
  int rlo = lane & 15, khi = lane >> 4;
  int row0 = blockIdx.x * 64 + w * 16;
  const unsigned short* zr = z1b + (size_t)(row0 + rlo) * 128;
  f32x4 acc[4];
#pragma unroll
  for (int ct = 0; ct < 4; ++ct) { acc[ct][0] = 0.f; acc[ct][1] = 0.f; acc[ct][2] = 0.f; acc[ct][3] = 0.f; }
#pragma unroll
  for (int kc = 0; kc < 4; ++kc) {
    int k0 = kc * 32 + khi * 8;
    union { bf16x8 b; unsigned short u[8]; } raw, af;
    raw.b = *(const bf16x8*)(zr + k0);
#pragma unroll
    for (int j = 0; j < 8; ++j) {
      float vf = fmaf(bf2f(raw.u[j]), scl[k0 + j], shf[k0 + j]);
      af.u[j] = f2bf(fmaxf(vf, 0.f));
    }
#pragma unroll
    for (int ct = 0; ct < 4; ++ct) {
      const bf16x8* bp = (const bf16x8*)(Wt + ((size_t)(ct * 16 + rlo) * 128 + k0));
      acc[ct] = __builtin_amdgcn_mfma_f32_16x16x32_bf16(af.b, bp[0], acc[ct], 0, 0, 0);
    }
  }
#pragma unroll
  for (int ct = 0; ct < 4; ++ct) {
    int c = ct * 16 + rlo;
    float bs = bias[c];
    float s = 0.f, s2 = 0.f;
#pragma unroll
    for (int q = 0; q < 4; ++q) {
      int row = row0 + khi * 4 + q;
      float v = acc[ct][q] + bs;
      unsigned short ub = f2bf(v);
      z2b[(size_t)row * 64 + c] = ub;
      float vf = bf2f(ub);
      if (row < NN) { s += vf; s2 += vf * vf; }
    }
    atomicAdd(&sred[c], s);
    atomicAdd(&sred[64 + c], s2);
  }
  __syncthreads();
  if (tid < 128) atomicAdd(&stat2f[(blockIdx.x & 7) * 128 + tid], sred[tid]);
}

// ---------------- BN2 finalize -> scl/shf (64 channels) ----------------
__global__ void finalize2_k(const float* __restrict__ stat2f,
                            const float* __restrict__ g,
                            const float* __restrict__ be,
                            float* __restrict__ scl, float* __restrict__ shf) {
  int c = threadIdx.x;   // 64 threads
  float s = 0.f, s2 = 0.f;
#pragma unroll
  for (int r = 0; r < 8; ++r) { s += stat2f[r * 128 + c]; s2 += stat2f[r * 128 + 64 + c]; }
  float mean = s * (1.f / NN);
  float var = fmaxf(s2 * (1.f / NN) - mean * mean, 0.f);
  float sc = g[c] * rsqrtf(var + EPS);
  scl[c] = sc;
  shf[c] = be[c] - mean * sc;
}

// ---------------- final BN apply (no relu) -> f32 h output ----------------
__global__ __launch_bounds__(256) void bn_final_k(const unsigned short* __restrict__ A,
                                                  const float* __restrict__ scl,
                                                  const float* __restrict__ shf,
                                                  float* __restrict__ hf) {
  int i = blockIdx.x * 256 + threadIdx.x;   // NN*8 exactly
  int n = i >> 3, c0 = (i & 7) * 8;
  union { bf16x8 b; unsigned short u[8]; } raw;
  raw.b = *(const bf16x8*)(A + (size_t)n * 64 + c0);
  float v[8];
#pragma unroll
  for (int j = 0; j < 8; ++j) v[j] = fmaf(bf2f(raw.u[j]), scl[c0 + j], shf[c0 + j]);
  float* p = hf + (size_t)n * 64 + c0;
  *(float4*)(p)     = make_float4(v[0], v[1], v[2], v[3]);
  *(float4*)(p + 4) = make_float4(v[4], v[5], v[6], v[7]);
}

// ---------------- pool: xpool[batch[n]] += h[n]  (batch sorted) ----------------
__global__ __launch_bounds__(256) void pool_k(const float* __restrict__ h,
                                              const int* __restrict__ batch,
                                              float* __restrict__ xpool) {
  int n0 = blockIdx.x * 16;
  int tid = threadIdx.x;
  int r = tid >> 4, c4 = tid & 15;
  int n = n0 + r;
  float4 v = *(const float4*)(h + (size_t)n * 64 + c4 * 4);
  __shared__ int gfirst, gsame;
  __shared__ float red[16][64];
  if (tid == 0) {
    gfirst = batch[n0];
    gsame = (batch[n0] == batch[n0 + 15]) ? 1 : 0;
  }
  *(float4*)&red[r][c4 * 4] = v;
  __syncthreads();
  if (gsame) {
#pragma unroll
    for (int off = 8; off >= 1; off >>= 1) {
      if (r < off) {
        float4 a = *(float4*)&red[r][c4 * 4];
        float4 b = *(float4*)&red[r + off][c4 * 4];
        *(float4*)&red[r][c4 * 4] = make_float4(a.x + b.x, a.y + b.y, a.z + b.z, a.w + b.w);
      }
      __syncthreads();
    }
    if (r == 0) {
      float* p = xpool + (size_t)gfirst * 64 + c4 * 4;
      float4 a = *(float4*)&red[0][c4 * 4];
      atomicAdd(p + 0, a.x); atomicAdd(p + 1, a.y);
      atomicAdd(p + 2, a.z); atomicAdd(p + 3, a.w);
    }
  } else {
    int g = batch[n];
    float* p = xpool + (size_t)g * 64 + c4 * 4;
    atomicAdd(p + 0, v.x); atomicAdd(p + 1, v.y);
    atomicAdd(p + 2, v.z); atomicAdd(p + 3, v.w);
  }
}

extern "C" void kernel_launch(void* const* d_in, const int* in_sizes, int n_in,
                              void* d_out, int out_size, void* d_ws, size_t ws_size,
                              hipStream_t stream) {
  const int* batch = (const int*)d_in[0];
  const int* x = (const int*)d_in[1];
  const int* ei = (const int*)d_in[2];
  const int* eattr = (const int*)d_in[3];
  const float* atom_emb = (const float*)d_in[4];
  const float* bond_emb = (const float*)d_in[5];
  const float* W1 = (const float*)d_in[6];
  const float* b1 = (const float*)d_in[7];
  const float* g1 = (const float*)d_in[8];
  const float* be1 = (const float*)d_in[9];
  const float* W2 = (const float*)d_in[10];
  const float* b2 = (const float*)d_in[11];
  const float* gbn = (const float*)d_in[12];
  const float* bbn = (const float*)d_in[13];

  float* out = (float*)d_out;
  float* xpool = out;               // 256*64
  float* hf = out + NG * 64;        // final f32 h lives directly in output

  char* ws = (char*)d_ws;
  unsigned short* A   = (unsigned short*)(ws);                      // NP*64 bf16 (h / z2)
  unsigned short* B   = (unsigned short*)(ws + 12804096);           // NP*64 bf16 (z = h+aggr)
  unsigned short* z1b = (unsigned short*)(ws + 25608192);           // NP*128 bf16
  float* statf        = (float*)(ws + 51216384);                    // 12 KB
  float* stat1f = statf;
  float* stat2f = statf + 2048;
  float* scl2         = (float*)(ws + 51228672);                    // 64 f32
  float* shf2         = scl2 + 64;
  unsigned short* Wt1 = (unsigned short*)(ws + 51229184);           // 5*128*64 bf16
  unsigned short* Wt2 = (unsigned short*)(ws + 51311104);           // 5*64*128 bf16
  int* rowstart       = (int*)(ws + 51393024);                      // NN+1 ints
  int* epack          = (int*)(ws + 51793152);                      // NE ints
  // CSR build temporaries alias z1b region (dead until first gemm1)
  int* cnt    = (int*)(ws + 25608192);
  int* cursor = (int*)(ws + 25608192 + 1048576);
  int* bsum   = (int*)(ws + 25608192 + 2097152);
  int* bofs   = bsum + 128;

  init_h_k<<<NN * 8 / 256, 256, 0, stream>>>(x, atom_emb, A);
  wconv_k<<<(2 * NL * 128 * 64 + 255) / 256, 256, 0, stream>>>(W1, W2, Wt1, Wt2);

  // ---- CSR build (edge structure shared by all layers) ----
  hipMemsetAsync(cnt, 0, (size_t)NN * 4, stream);
  hist_k<<<(NE + 255) / 256, 256, 0, stream>>>(ei, cnt);
  scan1_k<<<98, 256, 0, stream>>>(cnt, rowstart, bsum);
  scan2_k<<<1, 64, 0, stream>>>(bsum, bofs, 98);
  scan3_k<<<(NN + 255) / 256, 256, 0, stream>>>(rowstart, bofs, cursor);
  scatter_k<<<8 * ((NE + 255) / 256), 256, 0, stream>>>(ei, eattr, cursor, epack);

  for (int l = 0; l < NL; ++l) {
    if (l == 0)
      csr_aggr_k<0><<<NN / 4, 256, 0, stream>>>(rowstart, epack, bond_emb, A, scl2, shf2, B);
    else
      csr_aggr_k<1><<<NN / 4, 256, 0, stream>>>(rowstart, epack, bond_emb, A, scl2, shf2, B);
    hipMemsetAsync(statf, 0, 12288, stream);
    gemm1_k<<<(NN + 63) / 64, 256, 0, stream>>>(B, Wt1 + (size_t)l * 128 * 64,
                                                b1 + (size_t)l * 128, z1b, stat1f);
    gemm2_k<<<(NN + 63) / 64, 256, 0, stream>>>(z1b, Wt2 + (size_t)l * 64 * 128,
                                                b2 + (size_t)l * 64,
                                                g1 + (size_t)l * 128, be1 + (size_t)l * 128,
                                                stat1f, A, stat2f);
    finalize2_k<<<1, 64, 0, stream>>>(stat2f, gbn + (size_t)l * 64, bbn + (size_t)l * 64,
                                      scl2, shf2);
  }

  bn_final_k<<<NN * 8 / 256, 256, 0, stream>>>(A, scl2, shf2, hf);

  hipMemsetAsync(xpool, 0, (size_t)NG * 64 * 4, stream);
  pool_k<<<NN / 16, 256, 0, stream>>>(hf, batch, xpool);
}